// Round 12
// baseline (221.772 us; speedup 1.0000x reference)
//
#include <hip/hip_runtime.h>
#include <cstdint>
#include <cstddef>

typedef __attribute__((ext_vector_type(8))) short short8;
typedef __attribute__((ext_vector_type(4))) short short4v;
typedef __attribute__((ext_vector_type(4))) float floatx4;
typedef __attribute__((ext_vector_type(4))) unsigned short ushort4v;

#if defined(__has_builtin)
#  if __has_builtin(__builtin_amdgcn_mfma_f32_16x16x16bf16_1k)
#    define HAVE_MFMA16 1
#  endif
#endif

#define NB 2
#define NPIX 2304
#define TBL 9025
#define TBLP 9032                      // padded
#define L2E 1.4426950408889634f
#define QSCALE 0.17677669529663689f    // 1/sqrt(32)

__device__ __forceinline__ float b2f(unsigned short u) {
  union { unsigned int i; float f; } v; v.i = ((unsigned int)u) << 16; return v.f;
}
__device__ __forceinline__ unsigned short f2b(float f) {
  union { float f; unsigned int i; } v; v.f = f;
  return (unsigned short)((v.i + 0x7fffu + ((v.i >> 16) & 1u)) >> 16);
}
__device__ __forceinline__ unsigned int f2b2_fast(float lo, float hi) {
  union { float f; unsigned int i; } a, b; a.f = lo; b.f = hi;
  return ((a.i + 0x8000u) >> 16) | (((b.i + 0x8000u) >> 16) << 16);
}
__device__ __forceinline__ float hi2f(unsigned int u) {
  union { unsigned int i; float f; } v; v.i = u & 0xffff0000u; return v.f;
}
__device__ __forceinline__ float lo2f(unsigned int u) {
  union { unsigned int i; float f; } v; v.i = u << 16; return v.f;
}

// ---------------------------------------------------------------------------
// Prep: fp32->bf16 weights + per-head bias PAIR table:
// tabp[h][e] = dword( bf16(tab[e]*L2E), bf16(tab[e+1]*L2E) )  (lo, hi)
// ---------------------------------------------------------------------------
__global__ __launch_bounds__(256) void prep_k(
    const float* __restrict__ gamma, const float* __restrict__ wqkv,
    const float* __restrict__ wout, const float* __restrict__ table,
    unsigned short* __restrict__ gb, unsigned short* __restrict__ qb,
    unsigned short* __restrict__ wb, unsigned int* __restrict__ tabp)
{
  int i = blockIdx.x * 256 + threadIdx.x;
  if (i < 65536)  gb[i] = f2b(gamma[i]);
  if (i < 196608) qb[i] = f2b(wqkv[i]);
  if (i < 65536)  wb[i] = f2b(wout[i]);
  if (i < TBL * 8) {
    int e = i >> 3, h = i & 7;
    int e1 = (e + 1 < TBL) ? e + 1 : e;
    unsigned int lo = f2b(table[(size_t)e * 8 + h] * L2E);
    unsigned int hi = f2b(table[(size_t)e1 * 8 + h] * L2E);
    tabp[(size_t)h * TBLP + e] = lo | (hi << 16);
  }
}

// ---------------------------------------------------------------------------
// 64x64-tile bf16 MFMA GEMM, K=256, N=2304 per batch (unchanged from r11).
// ---------------------------------------------------------------------------
template<int MODE>
__global__ __launch_bounds__(256) void gemm_k(
    const unsigned short* __restrict__ A,
    const void* __restrict__ Bv,
    const float* __restrict__ vec,
    unsigned short* __restrict__ o0,
    unsigned short* __restrict__ o1,
    unsigned short* __restrict__ o2,
    float* __restrict__ of)
{
  __shared__ unsigned short Al[64][40];
  __shared__ unsigned short Bl[64][40];
  const float* __restrict__ X = (const float*)Bv;
  const unsigned short* __restrict__ Bw = (const unsigned short*)Bv;

  const int n0 = blockIdx.x * 64;
  const int m0 = blockIdx.y * 64;
  const int b  = blockIdx.z;
  const int tid = threadIdx.x;
  const int wave = tid >> 6, lane = tid & 63;
  const int wm = wave >> 1, wn = wave & 1;
  const int lm = lane & 15, quad = lane >> 4;

  floatx4 acc[2][2] = {};

  for (int k0 = 0; k0 < 256; k0 += 32) {
    __syncthreads();
    {
      int ml = tid >> 2, ko = (tid & 3) * 8;
      *(short8*)&Al[ml][ko] = *(const short8*)&A[(size_t)(m0 + ml) * 256 + k0 + ko];
    }
    if (MODE == 0) {
      int kk = tid >> 3, n8 = (tid & 7) * 8;
      const float* xr = &X[((size_t)(b * 256 + k0 + kk)) * NPIX + n0 + n8];
      float4 x0 = *(const float4*)xr;
      float4 x1 = *(const float4*)(xr + 4);
      Bl[n8 + 0][kk] = f2b(x0.x * x0.x);
      Bl[n8 + 1][kk] = f2b(x0.y * x0.y);
      Bl[n8 + 2][kk] = f2b(x0.z * x0.z);
      Bl[n8 + 3][kk] = f2b(x0.w * x0.w);
      Bl[n8 + 4][kk] = f2b(x1.x * x1.x);
      Bl[n8 + 5][kk] = f2b(x1.y * x1.y);
      Bl[n8 + 6][kk] = f2b(x1.z * x1.z);
      Bl[n8 + 7][kk] = f2b(x1.w * x1.w);
    } else {
      int nl = tid >> 2, ko = (tid & 3) * 8;
      short8 bv = *(const short8*)&Bw[((size_t)b * NPIX + n0 + nl) * 256 + k0 + ko];
      *(short8*)&Bl[nl][ko] = bv;
    }
    __syncthreads();
    short8 af[2], bfr[2];
    #pragma unroll
    for (int tm = 0; tm < 2; ++tm)
      af[tm] = *(const short8*)&Al[wm*32 + tm*16 + lm][quad*8];
    #pragma unroll
    for (int tn = 0; tn < 2; ++tn)
      bfr[tn] = *(const short8*)&Bl[wn*32 + tn*16 + lm][quad*8];
    #pragma unroll
    for (int tm = 0; tm < 2; ++tm)
      #pragma unroll
      for (int tn = 0; tn < 2; ++tn)
        acc[tm][tn] = __builtin_amdgcn_mfma_f32_16x16x32_bf16(af[tm], bfr[tn], acc[tm][tn], 0, 0, 0);
  }

  #pragma unroll
  for (int tm = 0; tm < 2; ++tm) {
    const int rbase = m0 + wm*32 + tm*16 + quad*4;
    #pragma unroll
    for (int tn = 0; tn < 2; ++tn) {
      const int col = n0 + wn*32 + tn*16 + lm;
      floatx4 a4 = acc[tm][tn];
      if (MODE == 0) {
        ushort4v pk;
        #pragma unroll
        for (int r = 0; r < 4; ++r) {
          int d = rbase + r;
          float xv = X[((size_t)(b * 256 + d)) * NPIX + col];
          pk[r] = f2b(xv * rsqrtf(vec[d] + a4[r]));
        }
        *(ushort4v*)&o0[((size_t)(b * NPIX + col)) * 256 + rbase] = pk;
      } else if (MODE == 1) {
        const int part = rbase >> 8, h = (rbase >> 5) & 7, dd = rbase & 31;
        if (part == 2) {           // V transposed: [b][h][d][n]
          #pragma unroll
          for (int r = 0; r < 4; ++r)
            o2[(((size_t)(b * 8 + h)) * 32 + dd + r) * NPIX + col] = f2b(a4[r]);
        } else {
          unsigned short* dst = part == 0 ? o0 : o1;
          const float sc = (part == 0) ? (QSCALE * L2E) : 1.0f;
          ushort4v pk;
          #pragma unroll
          for (int r = 0; r < 4; ++r) pk[r] = f2b(a4[r] * sc);
          *(ushort4v*)&dst[(((size_t)(b * 8 + h)) * NPIX + col) * 32 + dd] = pk;
        }
      } else {
        #pragma unroll
        for (int r = 0; r < 4; ++r) {
          int c = rbase + r;
          of[((size_t)(b * 256 + c)) * NPIX + col] = a4[r] + vec[c];
        }
      }
    }
  }
}

// ---------------------------------------------------------------------------
// MFMA flash attention, LDS-free K-loop. Block = 512 thr = 8 waves, key-split
// halves; XCD-swizzled 1D grid (blockIdx%8 == bh&7). Per 64-key tile:
//   S^T = K*Q^T (4 mfma 16x16x32, K frags direct global)
//   bias: 2 packed-bf16-pair dwords per kt from L2 (compute-independent,
//   prefetched); p = v_exp_f32; PV via mfma 16x16x16 whose B-frag granularity
//   (4 keys/quad) EXACTLY matches the S^T C-layout -> s4[kt] packs directly
//   into the PV B-operand, no transpose, no LDS. Fallback (no 16x16x16
//   builtin): r11 shuffle transpose + 16x16x32.
// ---------------------------------------------------------------------------
__global__ __launch_bounds__(512, 4) void attn_k(
    const unsigned short* __restrict__ qg, const unsigned short* __restrict__ kg,
    const unsigned short* __restrict__ vt, const unsigned int* __restrict__ tabp_g,
    unsigned short* __restrict__ ob)
{
  __shared__ __align__(16) float Om[8][16][36];   // 18.4 KB partial O
  __shared__ float lpart[2][4][16];

  const int tid = threadIdx.x;
  const int w = tid >> 6, lane = tid & 63;
  const int lm = lane & 15, quad = lane >> 4;
  const int gq = w & 3, half = w >> 2;
  const int bi = blockIdx.x;
  const int bh = (bi & 7) + 8 * ((bi >> 3) & 1);
  const int q0 = (bi >> 4) * 64;
  const size_t base = (size_t)bh * NPIX * 32;
  const int j00 = half * 1152;
  const unsigned int* __restrict__ tp = tabp_g + (size_t)(bh & 7) * TBLP;

  const int q = q0 + gq * 16 + lm;
  const short8 qfrag = *(const short8*)&qg[base + (size_t)q * 32 + quad * 8];

  const int hi = (q * 43691) >> 21;                  // q / 48
  const int rb = (hi + 47) * 95 + (q - hi * 48) + 47;

  float lsum = 0.f;
  floatx4 o[2] = {};

  // ---- current-iteration register set ----
  short8 kf[4];
#ifdef HAVE_MFMA16
  short4v vf[8];     // [kt*2+dt], 4 bf16 each
#else
  short8 vf[4];      // [c*2+dt]
  const int sA = lm + 16 * (2 * (quad & 1));
  const int ktsel = quad >> 1;
#endif
  unsigned int bd[8];

  #pragma unroll
  for (int kt = 0; kt < 4; ++kt)
    kf[kt] = *(const short8*)&kg[base + (size_t)(j00 + kt * 16 + lm) * 32 + quad * 8];
#ifdef HAVE_MFMA16
  #pragma unroll
  for (int kt = 0; kt < 4; ++kt)
    #pragma unroll
    for (int dt = 0; dt < 2; ++dt)
      vf[kt * 2 + dt] = *(const short4v*)&vt[base + (size_t)(dt * 16 + lm) * NPIX + j00 + kt * 16 + quad * 4];
#else
  #pragma unroll
  for (int c = 0; c < 2; ++c)
    #pragma unroll
    for (int dt = 0; dt < 2; ++dt)
      vf[c * 2 + dt] = *(const short8*)&vt[base + (size_t)(dt * 16 + lm) * NPIX + j00 + c * 32 + quad * 8];
#endif
  #pragma unroll
  for (int kt = 0; kt < 4; ++kt) {
    const int key0 = j00 + kt * 16 + quad * 4;
    const int hj = (key0 * 43691) >> 21;
    const int ib = rb - key0 - hj * 47;
    bd[kt * 2 + 0] = tp[ib - 1];
    bd[kt * 2 + 1] = tp[ib - 3];
  }

  for (int t = 0; t < 18; ++t) {
    const int j0 = j00 + t * 64;
    const int j0n = j00 + (t < 17 ? t + 1 : t) * 64;

    // ---- prefetch next iteration (compute-independent addresses) ----
    short8 kn[4];
#ifdef HAVE_MFMA16
    short4v vn[8];
#else
    short8 vn[4];
#endif
    unsigned int bn[8];
    #pragma unroll
    for (int kt = 0; kt < 4; ++kt)
      kn[kt] = *(const short8*)&kg[base + (size_t)(j0n + kt * 16 + lm) * 32 + quad * 8];
#ifdef HAVE_MFMA16
    #pragma unroll
    for (int kt = 0; kt < 4; ++kt)
      #pragma unroll
      for (int dt = 0; dt < 2; ++dt)
        vn[kt * 2 + dt] = *(const short4v*)&vt[base + (size_t)(dt * 16 + lm) * NPIX + j0n + kt * 16 + quad * 4];
#else
    #pragma unroll
    for (int c = 0; c < 2; ++c)
      #pragma unroll
      for (int dt = 0; dt < 2; ++dt)
        vn[c * 2 + dt] = *(const short8*)&vt[base + (size_t)(dt * 16 + lm) * NPIX + j0n + c * 32 + quad * 8];
#endif
    #pragma unroll
    for (int kt = 0; kt < 4; ++kt) {
      const int key0 = j0n + kt * 16 + quad * 4;
      const int hj = (key0 * 43691) >> 21;
      const int ib = rb - key0 - hj * 47;
      bn[kt * 2 + 0] = tp[ib - 1];
      bn[kt * 2 + 1] = tp[ib - 3];
    }

    // ---- S^T = K * Q^T ----
    floatx4 s4[4];
    #pragma unroll
    for (int kt = 0; kt < 4; ++kt) {
      floatx4 z = {};
      s4[kt] = __builtin_amdgcn_mfma_f32_16x16x32_bf16(kf[kt], qfrag, z, 0, 0, 0);
    }
    // ---- bias + exp2 + pack ----
    unsigned int pp[4][2];
    #pragma unroll
    for (int kt = 0; kt < 4; ++kt) {
      const unsigned int d0 = bd[kt * 2 + 0], d1 = bd[kt * 2 + 1];
      float p0 = __builtin_amdgcn_exp2f(s4[kt][0] + hi2f(d0));
      float p1 = __builtin_amdgcn_exp2f(s4[kt][1] + lo2f(d0));
      float p2 = __builtin_amdgcn_exp2f(s4[kt][2] + hi2f(d1));
      float p3 = __builtin_amdgcn_exp2f(s4[kt][3] + lo2f(d1));
      lsum += (p0 + p1) + (p2 + p3);
      pp[kt][0] = f2b2_fast(p0, p1);
      pp[kt][1] = f2b2_fast(p2, p3);
    }
    // ---- PV ----
#ifdef HAVE_MFMA16
    #pragma unroll
    for (int kt = 0; kt < 4; ++kt) {
      unsigned int pr[2] = { pp[kt][0], pp[kt][1] };
      short4v pf = *(short4v*)pr;     // 4 bf16: keys quad*4+{0..3} of chunk kt
      #pragma unroll
      for (int dt = 0; dt < 2; ++dt)
        o[dt] = __builtin_amdgcn_mfma_f32_16x16x16bf16_1k(vf[kt * 2 + dt], pf, o[dt], 0, 0, 0);
    }
#else
    #pragma unroll
    for (int c = 0; c < 2; ++c) {
      short8 pf;
      #pragma unroll
      for (int g = 0; g < 4; ++g) {
        const int sl = sA + 16 * (g >> 1);
        unsigned int u0 = (unsigned int)__shfl((int)pp[2 * c + 0][g & 1], sl, 64);
        unsigned int u1 = (unsigned int)__shfl((int)pp[2 * c + 1][g & 1], sl, 64);
        unsigned int u = ktsel ? u1 : u0;
        pf[2 * g]     = (short)(u & 0xffffu);
        pf[2 * g + 1] = (short)(u >> 16);
      }
      #pragma unroll
      for (int dt = 0; dt < 2; ++dt)
        o[dt] = __builtin_amdgcn_mfma_f32_16x16x32_bf16(vf[c * 2 + dt], pf, o[dt], 0, 0, 0);
    }
#endif
    // ---- rotate prefetch ----
    #pragma unroll
    for (int i2 = 0; i2 < 4; ++i2) kf[i2] = kn[i2];
#ifdef HAVE_MFMA16
    #pragma unroll
    for (int i2 = 0; i2 < 8; ++i2) vf[i2] = vn[i2];
#else
    #pragma unroll
    for (int i2 = 0; i2 < 4; ++i2) vf[i2] = vn[i2];
#endif
    #pragma unroll
    for (int i2 = 0; i2 < 8; ++i2) bd[i2] = bn[i2];
  }

  // reduce l across the 4 quads holding the same query
  lsum += __shfl_xor(lsum, 16, 64);
  lsum += __shfl_xor(lsum, 32, 64);

  // write partials: Om[half*4+gq][q=16][36]
  {
    const int row = half * 4 + gq;
    #pragma unroll
    for (int dt = 0; dt < 2; ++dt)
      *(floatx4*)&Om[row][lm][dt * 16 + quad * 4] = o[dt];
    if (quad == 0) lpart[half][gq][lm] = lsum;
  }
  __syncthreads();

  // merge key-half partials
  if (w < 4) {
    const int qq = lane >> 2, dg = lane & 3;
    const float inv = 1.f / (lpart[0][w][qq] + lpart[1][w][qq]);
    const float* r0 = &Om[w][qq][dg * 8];
    const float* r1 = &Om[4 + w][qq][dg * 8];
    short8 pk;
    #pragma unroll
    for (int r = 0; r < 8; ++r)
      pk[r] = (short)f2b((r0[r] + r1[r]) * inv);
    *(short8*)&ob[base + (size_t)(q0 + w * 16 + qq) * 32 + dg * 8] = pk;
  }
}

// ---------------------------------------------------------------------------
extern "C" void kernel_launch(void* const* d_in, const int* in_sizes, int n_in,
                              void* d_out, int out_size, void* d_ws, size_t ws_size,
                              hipStream_t stream) {
  const float* x     = (const float*)d_in[0];
  const float* beta  = (const float*)d_in[1];
  const float* gamma = (const float*)d_in[2];
  const float* wqkv  = (const float*)d_in[3];
  const float* wout  = (const float*)d_in[4];
  const float* bout  = (const float*)d_in[5];
  const float* table = (const float*)d_in[6];
  float* out = (float*)d_out;

  unsigned short* ws = (unsigned short*)d_ws;
  const size_t NE = (size_t)NB * NPIX * 256;
  unsigned short* xn_t  = ws;
  unsigned short* qbuf  = ws + NE;
  unsigned short* kbuf  = ws + 2 * NE;
  unsigned short* vtbuf = ws + 3 * NE;
  unsigned short* obuf  = ws + 4 * NE;
  unsigned short* gam_b = obuf;
  unsigned short* qkv_b = obuf + 65536;
  unsigned short* out_b = ws + 5 * NE;
  unsigned int* tab_p = (unsigned int*)(ws + 5 * NE + 65536); // 8*TBLP dwords

  prep_k<<<768, 256, 0, stream>>>(gamma, wqkv, wout, table, gam_b, qkv_b, out_b, tab_p);
  gemm_k<0><<<dim3(36, 4, 2), 256, 0, stream>>>(gam_b, x, beta, xn_t, nullptr, nullptr, nullptr);
  gemm_k<1><<<dim3(36, 12, 2), 256, 0, stream>>>(qkv_b, xn_t, nullptr, qbuf, kbuf, vtbuf, nullptr);
  attn_k<<<576, 512, 0, stream>>>(qbuf, kbuf, vtbuf, tab_p, obuf);
  gemm_k<2><<<dim3(36, 4, 2), 256, 0, stream>>>(out_b, obuf, bout, nullptr, nullptr, nullptr, out);
}